// Round 1
// 435.768 us; speedup vs baseline: 1.2716x; 1.2716x over previous
//
#include <hip/hip_runtime.h>
#include <math.h>

// CRF layer: B=2048 sequences, T=512 max steps, C=32 tags.
// out = [ tags as float (B*T) | loss (1) ], total 1048577 floats.
#define BB 2048
#define TT 512
#define CC 32

#if __has_builtin(__builtin_amdgcn_exp2f)
#define EXP2F __builtin_amdgcn_exp2f
#else
#define EXP2F exp2f
#endif
#if __has_builtin(__builtin_amdgcn_logf)
#define LOG2F __builtin_amdgcn_logf   // v_log_f32 computes log2
#else
#define LOG2F log2f
#endif

#define LOG2E 1.4426950408889634f
#define LN2   0.6931471805599453f

__global__ void zero_loss_kernel(float* __restrict__ out) {
  if (threadIdx.x == 0) out[(size_t)BB * TT] = 0.0f;
}

// DPP row rotate-right by K: lane i reads lane (i-K)&15 within its 16-row.
#define ROR(dst, src, K)                                                     \
  dst = __int_as_float(__builtin_amdgcn_update_dpp(                          \
      0, __float_as_int(src), 0x120 | (K), 0xF, 0xF, false));

// Two waves per block, one batch element per block.
//   wave 0 (V): Viterbi recursion via LDS alpha exchange + backtrace + tags.
//   wave 1 (F): forward pass in SCALED LINEAR domain:
//       P_c = exp(alpha_c) * 2^-Acc  kept in registers;
//       per step: P'_c = exp(logit_c) * sum_p P_p * E[p][c], E = exp(trans)
//       precomputed once. 1 transcendental/step (prefetched exp(logit))
//       instead of 33. Rows split across lane halves: lower lanes accumulate
//       own 16-row via DPP ror, upper lanes the mirrored row (ds_bpermute'd
//       base), recombined via shfl_xor(32). Renormalize every 4 steps by the
//       wave-max's power-of-two exponent (exact v_ldexp, lane-uniform).
// Waves never sync. Within a wave, LDS write->read needs no barrier.
__global__ __launch_bounds__(128, 4) void crf_kernel(
    const float* __restrict__ logits,     // [B, T, C]
    const int*   __restrict__ seqlen,     // [B]
    const int*   __restrict__ labels,     // [B, T]
    const float* __restrict__ trans,      // [C, C]  trans[p*C + c]
    float*       __restrict__ out)        // [B*T + 1]
{
  __shared__ __align__(16) unsigned char bp_s[(TT - 1) * CC]; // 16,352 B
  __shared__ __align__(16) float avs[CC];       // viterbi alpha (natural)
  __shared__ unsigned char tag_s[TT];

  const int lane = threadIdx.x & 63;
  const int wv   = threadIdx.x >> 6;     // 0 = viterbi, 1 = forward
  const int b    = blockIdx.x;

  const int len = seqlen[b];
  const float* lg = logits + (size_t)b * TT * CC;
  const size_t bT = (size_t)b * TT;

  if (wv == 0) {
    // ================= Viterbi wave (LDS-based, proven-exact core) =========
    const int c = lane & 31;
    const int h = lane >> 5;

    float tr[16];
#pragma unroll
    for (int i = 0; i < 16; ++i) tr[i] = trans[(h * 16 + i) * CC + c];

    float av = lg[c];
    if (h == 0) avs[c] = av;

    const float4* avp = (const float4*)(avs + h * 16);

    // 3-deep logit prefetch, unclamped main loop + clamped tail
    const float* lgc = lg + c;
    float l0 = 0, l1 = 0, l2 = 0;
    {
      int r1 = 1 < len ? 1 : len - 1;
      int r2 = 2 < len ? 2 : len - 1;
      int r3 = 3 < len ? 3 : len - 1;
      l0 = lgc[r1 * CC]; l1 = lgc[r2 * CC]; l2 = lgc[r3 * CC];
    }

    auto vstep = [&](int t, float logit_c) {
      float pav[16];
#pragma unroll
      for (int qq = 0; qq < 4; ++qq) ((float4*)pav)[qq] = avp[qq];

      float S[16];
#pragma unroll
      for (int i = 0; i < 16; ++i) S[i] = pav[i] + tr[i];

      // tree max (depth 4)
      float m8[8];
#pragma unroll
      for (int k = 0; k < 8; ++k) m8[k] = fmaxf(S[k], S[k + 8]);
#pragma unroll
      for (int k = 0; k < 4; ++k) m8[k] = fmaxf(m8[k], m8[k + 4]);
      float best = fmaxf(fmaxf(m8[0], m8[2]), fmaxf(m8[1], m8[3]));

      // first-index = min index where equal (order-independent, exact)
      int t8[16];
#pragma unroll
      for (int i = 0; i < 16; ++i) t8[i] = (S[i] == best) ? i : 63;
#pragma unroll
      for (int k = 0; k < 8; ++k) t8[k] = min(t8[k], t8[k + 8]);
#pragma unroll
      for (int k = 0; k < 4; ++k) t8[k] = min(t8[k], t8[k + 4]);
      int bi = min(min(t8[0], t8[2]), min(t8[1], t8[3]));
      int bpi = h * 16 + bi;

      // cross-half combine (lower prev-tag wins ties)
      float ov = __shfl_xor(best, 32);
      int   oi = __shfl_xor(bpi, 32);
      bool take = (ov > best) || (ov == best && oi < bpi);
      best = take ? ov : best;
      bpi  = take ? oi : bpi;
      av = logit_c + best;

      if (h == 0) {
        avs[c] = av;
        bp_s[(t - 1) * CC + c] = (unsigned char)bpi;
      }
    };

    int t = 1;
    int tmain = len - 3;                   // t+3 <= len-1 guaranteed
    for (; t < tmain; ++t) {
      float lc = l0; l0 = l1; l1 = l2;
      l2 = lgc[(t + 3) * CC];
      vstep(t, lc);
    }
    for (; t < len; ++t) {
      float lc = l0; l0 = l1; l1 = l2;
      int rn = t + 3; rn = rn < len ? rn : len - 1;
      l2 = lgc[rn * CC];
      vstep(t, lc);
    }

    // last tag: argmax over c (first index on ties)
    float v = av; int idx = c;
#pragma unroll
    for (int d = 1; d < 32; d <<= 1) {
      float v2 = __shfl_xor(v, d, 32);
      int   i2 = __shfl_xor(idx, d, 32);
      if (v2 > v || (v2 == v && i2 < idx)) { v = v2; idx = i2; }
    }

    // backtrace: register-prefetched rows, in-register byte select
    if (lane == 0) {
      int tag = idx;
      tag_s[len - 1] = (unsigned char)tag;
      const uint4* bp4 = (const uint4*)bp_s;   // row r = bp4[2r], bp4[2r+1]
      uint4 Ra[3], Rb[3];
#pragma unroll
      for (int k = 0; k < 3; ++k) {
        int r = len - 2 - k;
        if (r >= 0) { Ra[k] = bp4[2 * r]; Rb[k] = bp4[2 * r + 1]; }
      }
      for (int tt = len - 1; tt > 0; --tt) {
        uint4 ua = Ra[0], ub = Rb[0];
        Ra[0] = Ra[1]; Rb[0] = Rb[1];
        Ra[1] = Ra[2]; Rb[1] = Rb[2];
        int r = tt - 4;
        if (r >= 0) { Ra[2] = bp4[2 * r]; Rb[2] = bp4[2 * r + 1]; }
        uint4 u4;
        u4.x = (tag & 16) ? ub.x : ua.x;
        u4.y = (tag & 16) ? ub.y : ua.y;
        u4.z = (tag & 16) ? ub.z : ua.z;
        u4.w = (tag & 16) ? ub.w : ua.w;
        unsigned lo = (tag & 8) ? u4.z : u4.x;
        unsigned hi = (tag & 8) ? u4.w : u4.y;
        unsigned u1 = (tag & 4) ? hi : lo;
        tag = (int)((u1 >> ((tag & 3) * 8)) & 0xffu);
        tag_s[tt - 1] = (unsigned char)tag;
      }
    }

    // coalesced tag store (+ zero padding)
#pragma unroll
    for (int j = 0; j < 8; ++j) {
      int tt = lane + 64 * j;
      float val = (tt < len) ? (float)tag_s[tt] : 0.0f;
      out[bT + tt] = val;
    }

  } else {
    // ================= Forward wave (scaled linear domain) =================
    const int* lab = labels + (size_t)b * TT;
    const int i = lane & 15;
    const int r = (lane >> 4) & 1;        // row of own column c
    const int c = lane & 31;              // lanes 32-63 mirror columns 0-31
    const int pr = (lane < 32) ? r : (1 - r);   // prev-row this lane reduces
    // bpermute source: lower lanes read own P, upper lanes read column c^16
    const int bpaddr = ((lane < 32) ? lane : (lane ^ 16)) << 2;

    // E[k] = exp(trans[pr*16 + ((i-k)&15)][c]) in DPP-rotation order
    float E[16];
#pragma unroll
    for (int k = 0; k < 16; ++k) {
      int p = pr * 16 + ((i - k) & 15);
      E[k] = EXP2F(trans[p * CC + c] * LOG2E);
    }

    float P   = EXP2F(lg[c] * LOG2E);  // scaled linear alpha for column c
    float Acc = 0.0f;                  // accumulated log2 scale (lane-uniform)

    // 3-deep prefetch of exp(logit): exp computed at load time, off-chain
    const float* lgc = lg + c;
    float e0 = 0, e1 = 0, e2 = 0;
    {
      int r1 = 1 < len ? 1 : len - 1;
      int r2 = 2 < len ? 2 : len - 1;
      int r3 = 3 < len ? 3 : len - 1;
      e0 = EXP2F(lgc[r1 * CC] * LOG2E);
      e1 = EXP2F(lgc[r2 * CC] * LOG2E);
      e2 = EXP2F(lgc[r3 * CC] * LOG2E);
    }

    auto fstep = [&](float el) {
      // base alpha vector for this lane's prev-row (1 DS op)
      float base = __int_as_float(
          __builtin_amdgcn_ds_bpermute(bpaddr, __float_as_int(P)));
      float x;
      float a0 = base * E[0];
      ROR(x, base, 1);  float a1 = x * E[1];
      ROR(x, base, 2);  float a2 = x * E[2];
      ROR(x, base, 3);  float a3 = x * E[3];
      ROR(x, base, 4);  a0 = fmaf(x, E[4],  a0);
      ROR(x, base, 5);  a1 = fmaf(x, E[5],  a1);
      ROR(x, base, 6);  a2 = fmaf(x, E[6],  a2);
      ROR(x, base, 7);  a3 = fmaf(x, E[7],  a3);
      ROR(x, base, 8);  a0 = fmaf(x, E[8],  a0);
      ROR(x, base, 9);  a1 = fmaf(x, E[9],  a1);
      ROR(x, base, 10); a2 = fmaf(x, E[10], a2);
      ROR(x, base, 11); a3 = fmaf(x, E[11], a3);
      ROR(x, base, 12); a0 = fmaf(x, E[12], a0);
      ROR(x, base, 13); a1 = fmaf(x, E[13], a1);
      ROR(x, base, 14); a2 = fmaf(x, E[14], a2);
      ROR(x, base, 15); a3 = fmaf(x, E[15], a3);
      float part = (a0 + a1) + (a2 + a3);      // this lane's 16-row partial
      float oth  = __shfl_xor(part, 32);       // other half's row partial
      float s    = part + oth;                 // commutative: halves lockstep
      P = el * s;
    };

    auto renorm = [&]() {
      // order-independent wave max -> identical on all lanes
      float m = P;
#pragma unroll
      for (int d = 1; d < 32; d <<= 1) m = fmaxf(m, __shfl_xor(m, d, 32));
      int e = (int)(__float_as_uint(m) >> 23) - 127;  // floor(log2 m)
      P = ldexpf(P, -e);                              // exact scaling
      Acc += (float)e;
    };

    int t = 1;
    int tmain = len - 3;
    for (; t < tmain; ++t) {
      float ec = e0; e0 = e1; e1 = e2;
      e2 = EXP2F(lgc[(t + 3) * CC] * LOG2E);
      fstep(ec);
      if ((t & 3) == 0) renorm();
    }
    for (; t < len; ++t) {
      float ec = e0; e0 = e1; e1 = e2;
      int rn = t + 3; rn = rn < len ? rn : len - 1;
      e2 = EXP2F(lgc[rn * CC] * LOG2E);
      fstep(ec);
      if ((t & 3) == 0) renorm();
    }

    // gold-path score (unary + binary), lane-parallel over t
    float uacc = 0.0f, bacc = 0.0f;
#pragma unroll
    for (int j = 0; j < 8; ++j) {
      int tt = lane + 64 * j;
      if (tt < len) {
        int lt = lab[tt];
        uacc += lg[tt * CC + lt];
        if (tt + 1 < len) {
          int ln = lab[tt + 1];
          bacc += trans[lt * CC + ln];
        }
      }
    }
#pragma unroll
    for (int d = 32; d >= 1; d >>= 1) {
      uacc += __shfl_xor(uacc, d);
      bacc += __shfl_xor(bacc, d);
    }

    // log partition: sum the 32 scaled alphas, add back the scale
    float ss = P;
#pragma unroll
    for (int d = 1; d < 32; d <<= 1) ss += __shfl_xor(ss, d, 32);
    float log_norm = LN2 * (Acc + LOG2F(ss));

    if (lane == 0) {
      float ll = uacc + bacc - log_norm;
      atomicAdd(out + (size_t)BB * TT, -ll * (1.0f / BB));
    }
  }
}

extern "C" void kernel_launch(void* const* d_in, const int* in_sizes, int n_in,
                              void* d_out, int out_size, void* d_ws, size_t ws_size,
                              hipStream_t stream) {
  const float* logits = (const float*)d_in[0];
  const int*   seqlen = (const int*)d_in[1];
  const int*   labels = (const int*)d_in[2];
  const float* trans  = (const float*)d_in[3];
  float* out = (float*)d_out;

  zero_loss_kernel<<<1, 64, 0, stream>>>(out);
  crf_kernel<<<dim3(BB), dim3(128), 0, stream>>>(logits, seqlen, labels, trans, out);
}

// Round 3
// 421.448 us; speedup vs baseline: 1.3148x; 1.0340x over previous
//
#include <hip/hip_runtime.h>
#include <math.h>

// CRF layer: B=2048 sequences, T=512 max steps, C=32 tags.
// out = [ tags as float (B*T) | loss (1) ], total 1048577 floats.
#define BB 2048
#define TT 512
#define CC 32

#if __has_builtin(__builtin_amdgcn_exp2f)
#define EXP2F __builtin_amdgcn_exp2f
#else
#define EXP2F exp2f
#endif
#if __has_builtin(__builtin_amdgcn_logf)
#define LOG2F __builtin_amdgcn_logf   // v_log_f32 computes log2
#else
#define LOG2F log2f
#endif

#define LOG2E 1.4426950408889634f
#define LN2   0.6931471805599453f

__global__ void zero_loss_kernel(float* __restrict__ out) {
  if (threadIdx.x == 0) out[(size_t)BB * TT] = 0.0f;
}

// Setup: counting-sort sequence indices by length (descending) into perm,
// and zero the loss accumulator. One block, TT=512 threads.
// Rationale: grid==resident capacity means no block refill; random lengths
// leave CUs half-drained (VALUBusy 46% ~ mean/max of uniform lens). Pairing
// longest-with-shortest makes every block's work ~ uniform (~513 steps).
__global__ void schedule_kernel(const int* __restrict__ seqlen,
                                int* __restrict__ perm,
                                float* __restrict__ out) {
  __shared__ int s[TT];
  __shared__ int off[TT];
  const int tid = threadIdx.x;
  if (tid == 0) out[(size_t)BB * TT] = 0.0f;
  s[tid] = 0;
  __syncthreads();
  for (int b = tid; b < BB; b += TT) atomicAdd(&s[seqlen[b] - 1], 1);
  __syncthreads();
  // inclusive suffix scan (Hillis-Steele), 9 rounds
  for (int d = 1; d < TT; d <<= 1) {
    int v = s[tid] + ((tid + d < TT) ? s[tid + d] : 0);
    __syncthreads();
    s[tid] = v;
    __syncthreads();
  }
  off[tid] = (tid + 1 < TT) ? s[tid + 1] : 0;  // exclusive suffix sum
  __syncthreads();
  for (int b = tid; b < BB; b += TT) {
    int pos = atomicAdd(&off[seqlen[b] - 1], 1);
    perm[pos] = b;  // descending length order (ties arbitrary)
  }
}

// DPP row rotate-right by K: lane i reads lane (i-K)&15 within its 16-row.
#define ROR(dst, src, K)                                                     \
  dst = __int_as_float(__builtin_amdgcn_update_dpp(                          \
      0, __float_as_int(src), 0x120 | (K), 0xF, 0xF, false));

// Two waves per block. If perm != nullptr, block k processes sequences
// perm[k] then perm[BB-1-k] (length-balanced pair); else block k processes
// just sequence k (fallback when no workspace is available).
//   wave 0 (V): Viterbi recursion via LDS alpha exchange + backtrace + tags.
//   wave 1 (F): forward pass in scaled linear domain (see R0 notes):
//       1 transcendental/step, DPP-rotation dot product, renorm every 4 steps.
// Waves never sync. Within a wave, LDS write->read needs no barrier.
__global__ __launch_bounds__(128, 4) void crf_kernel(
    const float* __restrict__ logits,     // [B, T, C]
    const int*   __restrict__ seqlen,     // [B]
    const int*   __restrict__ labels,     // [B, T]
    const float* __restrict__ trans,      // [C, C]  trans[p*C + c]
    float*       __restrict__ out,        // [B*T + 1]
    const int*   __restrict__ perm)       // [B] desc-length order, or nullptr
{
  __shared__ __align__(16) unsigned char bp_s[(TT - 1) * CC]; // 16,352 B
  __shared__ __align__(16) float avs[CC];       // viterbi alpha (natural)
  __shared__ unsigned char tag_s[TT];

  const int lane = threadIdx.x & 63;
  const int wv   = threadIdx.x >> 6;     // 0 = viterbi, 1 = forward
  const int k    = blockIdx.x;

  const int bs0 = perm ? perm[k] : k;
  const int bs1 = perm ? perm[BB - 1 - k] : -1;

  if (wv == 0) {
    // ================= Viterbi wave (LDS-based, proven-exact core) =========
    const int c = lane & 31;
    const int h = lane >> 5;

    float tr[16];                         // hoisted: shared by both seqs
#pragma unroll
    for (int i = 0; i < 16; ++i) tr[i] = trans[(h * 16 + i) * CC + c];

    const float4* avp = (const float4*)(avs + h * 16);

    for (int sq = 0; sq < 2; ++sq) {
      const int b = sq ? bs1 : bs0;
      if (b < 0) break;
      const int len = seqlen[b];
      const float* lg = logits + (size_t)b * TT * CC;
      const size_t bT = (size_t)b * TT;

      float av = lg[c];
      if (h == 0) avs[c] = av;

      // 3-deep logit prefetch, unclamped main loop + clamped tail
      const float* lgc = lg + c;
      float l0 = 0, l1 = 0, l2 = 0;
      {
        int r1 = 1 < len ? 1 : len - 1;
        int r2 = 2 < len ? 2 : len - 1;
        int r3 = 3 < len ? 3 : len - 1;
        l0 = lgc[r1 * CC]; l1 = lgc[r2 * CC]; l2 = lgc[r3 * CC];
      }

      auto vstep = [&](int t, float logit_c) {
        float pav[16];
#pragma unroll
        for (int qq = 0; qq < 4; ++qq) ((float4*)pav)[qq] = avp[qq];

        float S[16];
#pragma unroll
        for (int i = 0; i < 16; ++i) S[i] = pav[i] + tr[i];

        // tree max (depth 4)
        float m8[8];
#pragma unroll
        for (int kk = 0; kk < 8; ++kk) m8[kk] = fmaxf(S[kk], S[kk + 8]);
#pragma unroll
        for (int kk = 0; kk < 4; ++kk) m8[kk] = fmaxf(m8[kk], m8[kk + 4]);
        float best = fmaxf(fmaxf(m8[0], m8[2]), fmaxf(m8[1], m8[3]));

        // first-index = min index where equal (order-independent, exact)
        int t8[16];
#pragma unroll
        for (int i = 0; i < 16; ++i) t8[i] = (S[i] == best) ? i : 63;
#pragma unroll
        for (int kk = 0; kk < 8; ++kk) t8[kk] = min(t8[kk], t8[kk + 8]);
#pragma unroll
        for (int kk = 0; kk < 4; ++kk) t8[kk] = min(t8[kk], t8[kk + 4]);
        int bi = min(min(t8[0], t8[2]), min(t8[1], t8[3]));
        int bpi = h * 16 + bi;

        // cross-half combine (lower prev-tag wins ties)
        float ov = __shfl_xor(best, 32);
        int   oi = __shfl_xor(bpi, 32);
        bool take = (ov > best) || (ov == best && oi < bpi);
        best = take ? ov : best;
        bpi  = take ? oi : bpi;
        av = logit_c + best;

        if (h == 0) {
          avs[c] = av;
          bp_s[(t - 1) * CC + c] = (unsigned char)bpi;
        }
      };

      int t = 1;
      int tmain = len - 3;                 // t+3 <= len-1 guaranteed
      for (; t < tmain; ++t) {
        float lc = l0; l0 = l1; l1 = l2;
        l2 = lgc[(t + 3) * CC];
        vstep(t, lc);
      }
      for (; t < len; ++t) {
        float lc = l0; l0 = l1; l1 = l2;
        int rn = t + 3; rn = rn < len ? rn : len - 1;
        l2 = lgc[rn * CC];
        vstep(t, lc);
      }

      // last tag: argmax over c (first index on ties)
      float v = av; int idx = c;
#pragma unroll
      for (int d = 1; d < 32; d <<= 1) {
        float v2 = __shfl_xor(v, d, 32);
        int   i2 = __shfl_xor(idx, d, 32);
        if (v2 > v || (v2 == v && i2 < idx)) { v = v2; idx = i2; }
      }

      // backtrace: register-prefetched rows, in-register byte select
      if (lane == 0) {
        int tag = idx;
        tag_s[len - 1] = (unsigned char)tag;
        const uint4* bp4 = (const uint4*)bp_s;   // row r = bp4[2r], bp4[2r+1]
        uint4 Ra[3], Rb[3];
#pragma unroll
        for (int kk = 0; kk < 3; ++kk) {
          int r = len - 2 - kk;
          if (r >= 0) { Ra[kk] = bp4[2 * r]; Rb[kk] = bp4[2 * r + 1]; }
        }
        for (int tt = len - 1; tt > 0; --tt) {
          uint4 ua = Ra[0], ub = Rb[0];
          Ra[0] = Ra[1]; Rb[0] = Rb[1];
          Ra[1] = Ra[2]; Rb[1] = Rb[2];
          int r = tt - 4;
          if (r >= 0) { Ra[2] = bp4[2 * r]; Rb[2] = bp4[2 * r + 1]; }
          uint4 u4;
          u4.x = (tag & 16) ? ub.x : ua.x;
          u4.y = (tag & 16) ? ub.y : ua.y;
          u4.z = (tag & 16) ? ub.z : ua.z;
          u4.w = (tag & 16) ? ub.w : ua.w;
          unsigned lo = (tag & 8) ? u4.z : u4.x;
          unsigned hi = (tag & 8) ? u4.w : u4.y;
          unsigned u1 = (tag & 4) ? hi : lo;
          tag = (int)((u1 >> ((tag & 3) * 8)) & 0xffu);
          tag_s[tt - 1] = (unsigned char)tag;
        }
      }

      // coalesced tag store (+ zero padding)
#pragma unroll
      for (int j = 0; j < 8; ++j) {
        int tt = lane + 64 * j;
        float val = (tt < len) ? (float)tag_s[tt] : 0.0f;
        out[bT + tt] = val;
      }
    }

  } else {
    // ================= Forward wave (scaled linear domain) =================
    const int i = lane & 15;
    const int r = (lane >> 4) & 1;        // row of own column c
    const int c = lane & 31;              // lanes 32-63 mirror columns 0-31
    const int pr = (lane < 32) ? r : (1 - r);   // prev-row this lane reduces
    // bpermute source: lower lanes read own P, upper lanes read column c^16
    const int bpaddr = ((lane < 32) ? lane : (lane ^ 16)) << 2;

    // E[k] = exp(trans[pr*16 + ((i-k)&15)][c]) in DPP-rotation order
    float E[16];                          // hoisted: shared by both seqs
#pragma unroll
    for (int kk = 0; kk < 16; ++kk) {
      int p = pr * 16 + ((i - kk) & 15);
      E[kk] = EXP2F(trans[p * CC + c] * LOG2E);
    }

    float loss_acc = 0.0f;

    for (int sq = 0; sq < 2; ++sq) {
      const int b = sq ? bs1 : bs0;
      if (b < 0) break;
      const int len = seqlen[b];
      const float* lg = logits + (size_t)b * TT * CC;
      const int* lab = labels + (size_t)b * TT;

      float P   = EXP2F(lg[c] * LOG2E);  // scaled linear alpha for column c
      float Acc = 0.0f;                  // accumulated log2 scale (uniform)

      // 3-deep prefetch of exp(logit): exp computed at load time, off-chain
      const float* lgc = lg + c;
      float e0 = 0, e1 = 0, e2 = 0;
      {
        int r1 = 1 < len ? 1 : len - 1;
        int r2 = 2 < len ? 2 : len - 1;
        int r3 = 3 < len ? 3 : len - 1;
        e0 = EXP2F(lgc[r1 * CC] * LOG2E);
        e1 = EXP2F(lgc[r2 * CC] * LOG2E);
        e2 = EXP2F(lgc[r3 * CC] * LOG2E);
      }

      auto fstep = [&](float el) {
        // base alpha vector for this lane's prev-row (1 DS op)
        float base = __int_as_float(
            __builtin_amdgcn_ds_bpermute(bpaddr, __float_as_int(P)));
        float x;
        float a0 = base * E[0];
        ROR(x, base, 1);  float a1 = x * E[1];
        ROR(x, base, 2);  float a2 = x * E[2];
        ROR(x, base, 3);  float a3 = x * E[3];
        ROR(x, base, 4);  a0 = fmaf(x, E[4],  a0);
        ROR(x, base, 5);  a1 = fmaf(x, E[5],  a1);
        ROR(x, base, 6);  a2 = fmaf(x, E[6],  a2);
        ROR(x, base, 7);  a3 = fmaf(x, E[7],  a3);
        ROR(x, base, 8);  a0 = fmaf(x, E[8],  a0);
        ROR(x, base, 9);  a1 = fmaf(x, E[9],  a1);
        ROR(x, base, 10); a2 = fmaf(x, E[10], a2);
        ROR(x, base, 11); a3 = fmaf(x, E[11], a3);
        ROR(x, base, 12); a0 = fmaf(x, E[12], a0);
        ROR(x, base, 13); a1 = fmaf(x, E[13], a1);
        ROR(x, base, 14); a2 = fmaf(x, E[14], a2);
        ROR(x, base, 15); a3 = fmaf(x, E[15], a3);
        float part = (a0 + a1) + (a2 + a3);      // this lane's 16-row partial
        float oth  = __shfl_xor(part, 32);       // other half's row partial
        float s    = part + oth;                 // commutative: halves lockstep
        P = el * s;
      };

      auto renorm = [&]() {
        // order-independent wave max -> identical on all lanes
        float m = P;
#pragma unroll
        for (int d = 1; d < 32; d <<= 1) m = fmaxf(m, __shfl_xor(m, d, 32));
        int e = (int)(__float_as_uint(m) >> 23) - 127;  // floor(log2 m)
        P = ldexpf(P, -e);                              // exact scaling
        Acc += (float)e;
      };

      int t = 1;
      int tmain = len - 3;
      for (; t < tmain; ++t) {
        float ec = e0; e0 = e1; e1 = e2;
        e2 = EXP2F(lgc[(t + 3) * CC] * LOG2E);
        fstep(ec);
        if ((t & 3) == 0) renorm();
      }
      for (; t < len; ++t) {
        float ec = e0; e0 = e1; e1 = e2;
        int rn = t + 3; rn = rn < len ? rn : len - 1;
        e2 = EXP2F(lgc[rn * CC] * LOG2E);
        fstep(ec);
        if ((t & 3) == 0) renorm();
      }

      // gold-path score (unary + binary), lane-parallel over t
      float uacc = 0.0f, bacc = 0.0f;
#pragma unroll
      for (int j = 0; j < 8; ++j) {
        int tt = lane + 64 * j;
        if (tt < len) {
          int lt = lab[tt];
          uacc += lg[tt * CC + lt];
          if (tt + 1 < len) {
            int ln = lab[tt + 1];
            bacc += trans[lt * CC + ln];
          }
        }
      }
#pragma unroll
      for (int d = 32; d >= 1; d >>= 1) {
        uacc += __shfl_xor(uacc, d);
        bacc += __shfl_xor(bacc, d);
      }

      // log partition: sum the 32 scaled alphas, add back the scale
      float ss = P;
#pragma unroll
      for (int d = 1; d < 32; d <<= 1) ss += __shfl_xor(ss, d, 32);
      float log_norm = LN2 * (Acc + LOG2F(ss));

      loss_acc += (uacc + bacc - log_norm);
    }

    if (lane == 0) {
      atomicAdd(out + (size_t)BB * TT, loss_acc * (-1.0f / BB));
    }
  }
}

extern "C" void kernel_launch(void* const* d_in, const int* in_sizes, int n_in,
                              void* d_out, int out_size, void* d_ws, size_t ws_size,
                              hipStream_t stream) {
  const float* logits = (const float*)d_in[0];
  const int*   seqlen = (const int*)d_in[1];
  const int*   labels = (const int*)d_in[2];
  const float* trans  = (const float*)d_in[3];
  float* out = (float*)d_out;

  if (d_ws != nullptr && ws_size >= BB * sizeof(int)) {
    // Length-balanced pairing path: sort by length, pair long with short.
    int* perm = (int*)d_ws;
    schedule_kernel<<<1, TT, 0, stream>>>(seqlen, perm, out);
    crf_kernel<<<dim3(BB / 2), dim3(128), 0, stream>>>(
        logits, seqlen, labels, trans, out, perm);
  } else {
    // Fallback (no workspace): one sequence per block, proven R1 path.
    zero_loss_kernel<<<1, 64, 0, stream>>>(out);
    crf_kernel<<<dim3(BB), dim3(128), 0, stream>>>(
        logits, seqlen, labels, trans, out, nullptr);
  }
}